// Round 15
// baseline (170.866 us; speedup 1.0000x reference)
//
#include <hip/hip_runtime.h>
#include <math.h>

#define NPTS   100000
#define NRAYS  4096
#define KTOP   10
#define KMER   12
#define CAP    128
#define LCAP   12

// scan: 16 pts/lane (8 packed pairs), 4096 pts/block, 25 pblks x 64 rchunks
#define PPAIR  8
#define SBLK   25
#define RCS    64                 // ray chunks for scan
#define RPBS   (NRAYS / RCS)      // 64 rays per scan block

// theta: 512 blocks x 256 thr; block owns 8 rays; sample 32768 = 16 groups x
// 2048. Part = lane-index (64 parts of 512 pts); group loop unrolled x2.
#define TPAIR  4
#define NPART  64
#define TRAYS  8                  // rays per theta block
#define TGRP   16                 // point groups per block

typedef float v2f __attribute__((ext_vector_type(2)));

static_assert(SBLK * 4096 >= NPTS, "scan covers all points");
static_assert(TGRP * 2048 <= NPTS, "theta sample within real points");

__device__ __forceinline__ float4 make_center(const float* __restrict__ ro,
                                              const float* __restrict__ rd,
                                              int ray, float w) {
    float ox = ro[3 * ray + 0], oy = ro[3 * ray + 1], oz = ro[3 * ray + 2];
    float dx = rd[3 * ray + 0], dy = rd[3 * ray + 1], dz = rd[3 * ray + 2];
    float cx, cy, cz;
    {
#pragma clang fp contract(off)
        cx = ox + dx * 3.0f;
        cy = oy + dy * 3.0f;
        cz = oz + dz * 3.0f;
    }
    return make_float4(cx, cy, cz, w);
}

__device__ __forceinline__ float sigm(float x) { return 1.0f / (1.0f + expf(-x)); }

__device__ __forceinline__ unsigned long long mkkey(float sc, int id, bool v) {
    unsigned u = __float_as_uint(sc);
    u = (u & 0x80000000u) ? ~u : (u | 0x80000000u);    // order-preserving f32->u32
    unsigned long long k = ((unsigned long long)u << 32) | (unsigned)(~id);
    return v ? k : 0ull;                               // smaller id -> larger key
}

// ---------------------------------------------------------------------------
// theta: block = 8 rays, 256 threads, 512 blocks (2/CU). Sample = 32768 pts.
// Part p = lane index p (512 disjoint pts). Group loop UNROLLED x2: 48 loads
// in flight before compute — covers ~300cyc L2 latency at 2 waves/SIMD (the
// serial load->compute loop was theta's remaining stall). Lane maxima ->
// Msh[wave][ray][lane], 8 theta-lanes reduce -> theta; cnt=0.
// ---------------------------------------------------------------------------
__global__ __launch_bounds__(256, 2) void theta_kernel(const float* __restrict__ xyz,
                                                       const float* __restrict__ ro,
                                                       const float* __restrict__ rd,
                                                       float* __restrict__ theta,
                                                       int* __restrict__ cnt) {
    __shared__ float4 rsh[TRAYS];
    __shared__ float  Msh[4][TRAYS][64];               // 8 KB, lane-stride 1
    const int tid = threadIdx.x, wave = tid >> 6, lane = tid & 63;
    const int rbase = blockIdx.x * TRAYS;

    if (tid < TRAYS) rsh[tid] = make_center(ro, rd, rbase + tid, 0.0f);
    __syncthreads();

    float4 rr[TRAYS];
#pragma unroll
    for (int r = 0; r < TRAYS; ++r) rr[r] = rsh[r];    // rays -> registers, once

    v2f M[TRAYS];
#pragma unroll
    for (int r = 0; r < TRAYS; ++r) M[r] = (v2f){-INFINITY, -INFINITY};

#pragma unroll 1
    for (int g = 0; g < TGRP; g += 2) {                // 2 groups in flight
        v2f px[2][TPAIR], py[2][TPAIR], pz[2][TPAIR], pw[2][TPAIR];
#pragma unroll
        for (int h = 0; h < 2; ++h) {
            const int id0 = (g + h) * 2048 + wave * 512 + lane;
#pragma unroll
            for (int u = 0; u < TPAIR; ++u) {
                int ia = id0 + (2 * u) * 64, ib = id0 + (2 * u + 1) * 64;
                float xa = xyz[3 * ia + 0], ya = xyz[3 * ia + 1], za = xyz[3 * ia + 2];
                float xb = xyz[3 * ib + 0], yb = xyz[3 * ib + 1], zb = xyz[3 * ib + 2];
                px[h][u] = (v2f){xa, xb}; py[h][u] = (v2f){ya, yb}; pz[h][u] = (v2f){za, zb};
                pw[h][u] = (v2f){-0.5f * fmaf(xa, xa, fmaf(ya, ya, za * za)),
                                 -0.5f * fmaf(xb, xb, fmaf(yb, yb, zb * zb))};
            }
        }
#pragma unroll
        for (int r = 0; r < TRAYS; ++r) {
            const v2f rx = (v2f){rr[r].x, rr[r].x};
            const v2f ry = (v2f){rr[r].y, rr[r].y};
            const v2f rz = (v2f){rr[r].z, rr[r].z};
            v2f m = M[r];
#pragma unroll
            for (int h = 0; h < 2; ++h) {
#pragma unroll
                for (int u = 0; u < TPAIR; ++u) {
                    v2f t = __builtin_elementwise_fma(pz[h][u], rz, pw[h][u]);
                    t = __builtin_elementwise_fma(py[h][u], ry, t);
                    t = __builtin_elementwise_fma(px[h][u], rx, t);
                    m = __builtin_elementwise_max(m, t);
                }
            }
            M[r] = m;
        }
    }

#pragma unroll
    for (int r = 0; r < TRAYS; ++r)
        Msh[wave][r][lane] = fmaxf(M[r].x, M[r].y);    // lane-stride 1: no conflict
    __syncthreads();

    if (tid < TRAYS) {                                 // theta = 10th of 64 parts
        float vs[KTOP];
#pragma unroll
        for (int j = 0; j < KTOP; ++j) vs[j] = -INFINITY;
#pragma unroll 1
        for (int p = 0; p < NPART; ++p) {
            float v = fmaxf(fmaxf(Msh[0][tid][p], Msh[1][tid][p]),
                            fmaxf(Msh[2][tid][p], Msh[3][tid][p]));
#pragma unroll
            for (int t = KTOP - 1; t >= 1; --t) {
                bool up = v > vs[t - 1], here = v > vs[t];
                vs[t] = up ? vs[t - 1] : (here ? v : vs[t]);
            }
            vs[0] = fmaxf(vs[0], v);
        }
        theta[rbase + tid] = vs[KTOP - 1];
        cnt[rbase + tid] = 0;
    }
}

// ---------------------------------------------------------------------------
// scan: 16 pts/lane as 8 packed pairs (per-point fixed costs — ds_read,
// ballot gate, loop control, flush — amortized over 2x points vs R14).
// launch_bounds(256,2) prevents the compiler's 32-VGPR occupancy choice from
// re-materializing the point arrays (R11 trap). Emit >= theta to per-ray LDS
// buffers, bulk flush -> cand.
// ---------------------------------------------------------------------------
__global__ __launch_bounds__(256, 2) void scan_kernel(const float* __restrict__ xyz,
                                                      const float* __restrict__ ro,
                                                      const float* __restrict__ rd,
                                                      const float* __restrict__ theta,
                                                      int* __restrict__ cnt,
                                                      float2* __restrict__ cand) {
    __shared__ float4 rsh[RPBS];
    __shared__ int    lcnt[RPBS];
    __shared__ float2 lbuf[RPBS][LCAP];
    const int pblk = blockIdx.x, rchunk = blockIdx.y;
    const int tid = threadIdx.x, wave = tid >> 6, lane = tid & 63;
    const int rbase = rchunk * RPBS;

    if (tid < RPBS) {
        rsh[tid] = make_center(ro, rd, rbase + tid, theta[rbase + tid]);
        lcnt[tid] = 0;
    }

    const int id0 = pblk * 4096 + wave * 1024 + lane;
    v2f px[PPAIR], py[PPAIR], pz[PPAIR], pw[PPAIR];
#pragma unroll
    for (int u = 0; u < PPAIR; ++u) {
        int ia = id0 + (2 * u) * 64, ib = id0 + (2 * u + 1) * 64;
        bool va = ia < NPTS, vb = ib < NPTS;
        int ca = va ? ia : 0, cb = vb ? ib : 0;
        float xa = xyz[3 * ca + 0], ya = xyz[3 * ca + 1], za = xyz[3 * ca + 2];
        float xb = xyz[3 * cb + 0], yb = xyz[3 * cb + 1], zb = xyz[3 * cb + 2];
        px[u] = (v2f){xa, xb}; py[u] = (v2f){ya, yb}; pz[u] = (v2f){za, zb};
        pw[u] = (v2f){va ? -0.5f * fmaf(xa, xa, fmaf(ya, ya, za * za)) : -INFINITY,
                      vb ? -0.5f * fmaf(xb, xb, fmaf(yb, yb, zb * zb)) : -INFINITY};
    }
    __syncthreads();

    auto emit = [&](int r, float sc, int id) {
        int slot = atomicAdd(&lcnt[r], 1);             // LDS atomic
        float2 e = make_float2(sc, __int_as_float(id));
        if (slot < LCAP) lbuf[r][slot] = e;
        else {                                         // rare overflow
            int gs = atomicAdd(&cnt[rbase + r], 1);
            if (gs < CAP) cand[((rbase + r) << 7) + gs] = e;
        }
    };

#pragma unroll 2
    for (int r = 0; r < RPBS; ++r) {
        float4 rp = rsh[r];                            // direct LDS read
        const v2f rx = (v2f){rp.x, rp.x}, ry = (v2f){rp.y, rp.y}, rz = (v2f){rp.z, rp.z};
        v2f s[PPAIR];
        v2f a0, a1;
#pragma unroll
        for (int u = 0; u < PPAIR; ++u) {
            v2f t = __builtin_elementwise_fma(pz[u], rz, pw[u]);
            t = __builtin_elementwise_fma(py[u], ry, t);
            t = __builtin_elementwise_fma(px[u], rx, t);
            s[u] = t;
            if (u == 0)      a0 = t;
            else if (u == 1) a1 = t;
            else if (u & 1)  a1 = __builtin_elementwise_max(a1, t);
            else             a0 = __builtin_elementwise_max(a0, t);
        }
        v2f am = __builtin_elementwise_max(a0, a1);
        float hm = fmaxf(am.x, am.y);

        if (__ballot(hm >= rp.w)) {                    // rare wave-level gate
#pragma unroll
            for (int u = 0; u < PPAIR; ++u) {
                if (__ballot(s[u].x >= rp.w)) {        // per-element uniform gate
                    if (s[u].x >= rp.w) emit(r, s[u].x, id0 + (2 * u) * 64);
                }
                if (__ballot(s[u].y >= rp.w)) {
                    if (s[u].y >= rp.w) emit(r, s[u].y, id0 + (2 * u + 1) * 64);
                }
            }
        }
    }

    __syncthreads();
    if (tid < RPBS) {                                  // bulk flush: 1 atomic/ray
        int n = lcnt[tid];
        n = n < LCAP ? n : LCAP;
        if (n > 0) {
            const int rayid = rbase + tid;
            int base = atomicAdd(&cnt[rayid], n);
            for (int j = 0; j < n; ++j) {
                int slot = base + j;
                if (slot < CAP) cand[(rayid << 7) + slot] = lbuf[tid][j];
            }
        }
    }
}

// ---------------------------------------------------------------------------
// merge: wave per ray (proven R6 body). Coalesced candidate load, top-12 via
// 12 wave-argmax rounds on packed keys, parallel f64 re-rank, rgb.
// ---------------------------------------------------------------------------
__global__ __launch_bounds__(256) void merge_kernel(const float* __restrict__ ro,
                                                    const float* __restrict__ rd,
                                                    const int* __restrict__ cnt,
                                                    const float2* __restrict__ cand,
                                                    const float* __restrict__ xyz,
                                                    const float* __restrict__ fdc,
                                                    const float* __restrict__ opac,
                                                    float* __restrict__ out) {
    const int wave = threadIdx.x >> 6, lane = threadIdx.x & 63;
    const int ray = blockIdx.x * 4 + wave;

    int n = cnt[ray];
    n = n < CAP ? n : CAP;

    const float2* cl = cand + (ray << 7);
    float2 e0 = cl[lane];                              // coalesced 512B wave-load
    float2 e1 = cl[64 + lane];
    int id0 = __float_as_int(e0.y), id1 = __float_as_int(e1.y);

    unsigned long long k0 = mkkey(e0.x, id0, lane < n);
    unsigned long long k1 = mkkey(e1.x, id1, lane + 64 < n);

    int sel = -1;                                      // lane j holds j-th best id
    unsigned long long kl = k0 > k1 ? k0 : k1;
#pragma unroll
    for (int j = 0; j < KMER; ++j) {
        unsigned long long m = kl;
#pragma unroll
        for (int off = 1; off < 64; off <<= 1) {
            unsigned long long o = __shfl_xor(m, off);
            m = m > o ? m : o;
        }
        bool win = (kl == m) && (m != 0ull);
        int wid = (k0 >= k1) ? id0 : id1;
        unsigned long long wmask = __ballot(win);
        int wl = __ffsll(wmask) - 1;                   // unique winner (keys unique)
        int bid = __shfl(wid, wl & 63);
        if (m == 0ull) bid = -1;
        if (lane == j) sel = bid;
        if (win) {
            if (k0 >= k1) k0 = 0ull; else k1 = 0ull;
            kl = k0 > k1 ? k0 : k1;
        }
    }

    float ox = ro[3 * ray + 0], oy = ro[3 * ray + 1], oz = ro[3 * ray + 2];
    float dx = rd[3 * ray + 0], dy = rd[3 * ray + 1], dz = rd[3 * ray + 2];
    float cxf, cyf, czf;
    {
#pragma clang fp contract(off)
        cxf = ox + dx * 3.0f;
        cyf = oy + dy * 3.0f;
        czf = oz + dz * 3.0f;
    }
    double Cx = (double)cxf, Cy = (double)cyf, Cz = (double)czf;
    double cn = Cx * Cx + Cy * Cy + Cz * Cz;

    bool valid = (lane < KMER) && (sel >= 0);
    int pid = valid ? sel : 0;
    double X = (double)xyz[3 * pid + 0];
    double Y = (double)xyz[3 * pid + 1];
    double Z = (double)xyz[3 * pid + 2];
    double sq = valid ? (cn + (X * X + Y * Y + Z * Z) - 2.0 * (Cx * X + Cy * Y + Cz * Z))
                      : (double)INFINITY;
    int cid = valid ? sel : 0x7fffffff;

    int rank = 0;
#pragma unroll
    for (int k = 0; k < KMER; ++k) {                   // rank among the 12
        double sk = __shfl(sq, k);
        int    ik = __shfl(cid, k);
        if ((sk < sq) || (sk == sq && ik < cid)) ++rank;
    }

    bool take = valid && (rank < KTOP);
    float w = 0.0f, rr = 0.0f, gg = 0.0f, bb = 0.0f;
    if (take) {                                        // parallel gathers, 10 lanes
        float dd = sqrtf(fmaxf((float)sq, 0.0f));
        w  = expf(-0.1f * dd) * sigm(opac[pid]);
        rr = w * sigm(fdc[3 * pid + 0]);
        gg = w * sigm(fdc[3 * pid + 1]);
        bb = w * sigm(fdc[3 * pid + 2]);
    }
#pragma unroll
    for (int off = 1; off < 64; off <<= 1) {
        w  += __shfl_xor(w,  off);
        rr += __shfl_xor(rr, off);
        gg += __shfl_xor(gg, off);
        bb += __shfl_xor(bb, off);
    }
    if (lane == 0) {
        float inv = 1.0f / (w + 1e-8f);
        out[3 * ray + 0] = rr * inv;
        out[3 * ray + 1] = gg * inv;
        out[3 * ray + 2] = bb * inv;
    }
}

// ---------------------------------------------------------------------------
extern "C" void kernel_launch(void* const* d_in, const int* in_sizes, int n_in,
                              void* d_out, int out_size, void* d_ws, size_t ws_size,
                              hipStream_t stream) {
    const float* rays_o = (const float*)d_in[0];
    const float* rays_d = (const float*)d_in[1];
    const float* xyz    = (const float*)d_in[2];
    const float* fdc    = (const float*)d_in[3];
    const float* opac   = (const float*)d_in[4];
    float* out = (float*)d_out;

    // ws: theta 16KB | cnt 16KB | cand 4.0MB
    char* w = (char*)d_ws;
    float*  theta  = (float*)w;  w += (size_t)NRAYS * 4;
    int*    cnt    = (int*)w;    w += (size_t)NRAYS * 4;
    float2* cand   = (float2*)w;

    theta_kernel<<<NRAYS / TRAYS, 256, 0, stream>>>(xyz, rays_o, rays_d, theta, cnt);
    scan_kernel<<<dim3(SBLK, RCS), 256, 0, stream>>>(xyz, rays_o, rays_d, theta, cnt, cand);
    merge_kernel<<<NRAYS / 4, 256, 0, stream>>>(rays_o, rays_d, cnt, cand, xyz, fdc, opac, out);
}

// Round 16
// 149.466 us; speedup vs baseline: 1.1432x; 1.1432x over previous
//
#include <hip/hip_runtime.h>
#include <math.h>

#define NPTS   100000
#define NRAYS  4096
#define KTOP   10
#define KMER   12
#define CAP    128
#define LCAP   12

// scan: 8 pts/lane (4 packed pairs), 2048 pts/block, 49 pblks x 64 rchunks
#define PPAIR  4
#define SBLK   49
#define RCS    64                 // ray chunks for scan
#define RPBS   (NRAYS / RCS)      // 64 rays per scan block

// theta: 512 blocks x 256 thr; block owns 8 rays; sample 32768 = 16 groups x
// 2048. Part = lane-index (64 parts of 512 pts); group loop unrolled x2.
#define TPAIR  4
#define NPART  64
#define TRAYS  8                  // rays per theta block
#define TGRP   16                 // point groups per block

typedef float v2f __attribute__((ext_vector_type(2)));

static_assert(SBLK * 2048 >= NPTS, "scan covers all points");
static_assert(TGRP * 2048 <= NPTS, "theta sample within real points");

__device__ __forceinline__ float4 make_center(const float* __restrict__ ro,
                                              const float* __restrict__ rd,
                                              int ray, float w) {
    float ox = ro[3 * ray + 0], oy = ro[3 * ray + 1], oz = ro[3 * ray + 2];
    float dx = rd[3 * ray + 0], dy = rd[3 * ray + 1], dz = rd[3 * ray + 2];
    float cx, cy, cz;
    {
#pragma clang fp contract(off)
        cx = ox + dx * 3.0f;
        cy = oy + dy * 3.0f;
        cz = oz + dz * 3.0f;
    }
    return make_float4(cx, cy, cz, w);
}

__device__ __forceinline__ float sigm(float x) { return 1.0f / (1.0f + expf(-x)); }

__device__ __forceinline__ unsigned long long mkkey(float sc, int id, bool v) {
    unsigned u = __float_as_uint(sc);
    u = (u & 0x80000000u) ? ~u : (u | 0x80000000u);    // order-preserving f32->u32
    unsigned long long k = ((unsigned long long)u << 32) | (unsigned)(~id);
    return v ? k : 0ull;                               // smaller id -> larger key
}

// ---------------------------------------------------------------------------
// theta: block = 8 rays, 256 threads, 512 blocks (2/CU). Sample = 32768 pts.
// Part p = lane index p (512 disjoint pts). Group loop unrolled x2 (R15: ~-2us
// vs R14). Lane maxima -> Msh[wave][ray][lane] (conflict-free), 8 theta-lanes
// reduce across waves + top-10-of-64 insert -> theta; cnt=0.
// ---------------------------------------------------------------------------
__global__ __launch_bounds__(256, 2) void theta_kernel(const float* __restrict__ xyz,
                                                       const float* __restrict__ ro,
                                                       const float* __restrict__ rd,
                                                       float* __restrict__ theta,
                                                       int* __restrict__ cnt) {
    __shared__ float4 rsh[TRAYS];
    __shared__ float  Msh[4][TRAYS][64];               // 8 KB, lane-stride 1
    const int tid = threadIdx.x, wave = tid >> 6, lane = tid & 63;
    const int rbase = blockIdx.x * TRAYS;

    if (tid < TRAYS) rsh[tid] = make_center(ro, rd, rbase + tid, 0.0f);
    __syncthreads();

    float4 rr[TRAYS];
#pragma unroll
    for (int r = 0; r < TRAYS; ++r) rr[r] = rsh[r];    // rays -> registers, once

    v2f M[TRAYS];
#pragma unroll
    for (int r = 0; r < TRAYS; ++r) M[r] = (v2f){-INFINITY, -INFINITY};

#pragma unroll 1
    for (int g = 0; g < TGRP; g += 2) {                // 2 groups in flight
        v2f px[2][TPAIR], py[2][TPAIR], pz[2][TPAIR], pw[2][TPAIR];
#pragma unroll
        for (int h = 0; h < 2; ++h) {
            const int id0 = (g + h) * 2048 + wave * 512 + lane;
#pragma unroll
            for (int u = 0; u < TPAIR; ++u) {
                int ia = id0 + (2 * u) * 64, ib = id0 + (2 * u + 1) * 64;
                float xa = xyz[3 * ia + 0], ya = xyz[3 * ia + 1], za = xyz[3 * ia + 2];
                float xb = xyz[3 * ib + 0], yb = xyz[3 * ib + 1], zb = xyz[3 * ib + 2];
                px[h][u] = (v2f){xa, xb}; py[h][u] = (v2f){ya, yb}; pz[h][u] = (v2f){za, zb};
                pw[h][u] = (v2f){-0.5f * fmaf(xa, xa, fmaf(ya, ya, za * za)),
                                 -0.5f * fmaf(xb, xb, fmaf(yb, yb, zb * zb))};
            }
        }
#pragma unroll
        for (int r = 0; r < TRAYS; ++r) {
            const v2f rx = (v2f){rr[r].x, rr[r].x};
            const v2f ry = (v2f){rr[r].y, rr[r].y};
            const v2f rz = (v2f){rr[r].z, rr[r].z};
            v2f m = M[r];
#pragma unroll
            for (int h = 0; h < 2; ++h) {
#pragma unroll
                for (int u = 0; u < TPAIR; ++u) {
                    v2f t = __builtin_elementwise_fma(pz[h][u], rz, pw[h][u]);
                    t = __builtin_elementwise_fma(py[h][u], ry, t);
                    t = __builtin_elementwise_fma(px[h][u], rx, t);
                    m = __builtin_elementwise_max(m, t);
                }
            }
            M[r] = m;
        }
    }

#pragma unroll
    for (int r = 0; r < TRAYS; ++r)
        Msh[wave][r][lane] = fmaxf(M[r].x, M[r].y);    // lane-stride 1: no conflict
    __syncthreads();

    if (tid < TRAYS) {                                 // theta = 10th of 64 parts
        float vs[KTOP];
#pragma unroll
        for (int j = 0; j < KTOP; ++j) vs[j] = -INFINITY;
#pragma unroll 1
        for (int p = 0; p < NPART; ++p) {
            float v = fmaxf(fmaxf(Msh[0][tid][p], Msh[1][tid][p]),
                            fmaxf(Msh[2][tid][p], Msh[3][tid][p]));
#pragma unroll
            for (int t = KTOP - 1; t >= 1; --t) {
                bool up = v > vs[t - 1], here = v > vs[t];
                vs[t] = up ? vs[t - 1] : (here ? v : vs[t]);
            }
            vs[0] = fmaxf(vs[0], v);
        }
        theta[rbase + tid] = vs[KTOP - 1];
        cnt[rbase + tid] = 0;
    }
}

// ---------------------------------------------------------------------------
// scan: 8 pts/lane as 4 packed pairs, ray loop unrolled x4 with direct rsh
// reads, per-element ballot-gated emit to per-ray LDS buffers, bulk flush.
// [byte-identical to R14 — the 151.5us configuration; R15's PPAIR=8 variant
// regressed (grid 3136->1600 cost the TLP that hides the latency)]
// ---------------------------------------------------------------------------
__global__ __launch_bounds__(256) void scan_kernel(const float* __restrict__ xyz,
                                                   const float* __restrict__ ro,
                                                   const float* __restrict__ rd,
                                                   const float* __restrict__ theta,
                                                   int* __restrict__ cnt,
                                                   float2* __restrict__ cand) {
    __shared__ float4 rsh[RPBS];
    __shared__ int    lcnt[RPBS];
    __shared__ float2 lbuf[RPBS][LCAP];
    const int pblk = blockIdx.x, rchunk = blockIdx.y;
    const int tid = threadIdx.x, wave = tid >> 6, lane = tid & 63;
    const int rbase = rchunk * RPBS;

    if (tid < RPBS) {
        rsh[tid] = make_center(ro, rd, rbase + tid, theta[rbase + tid]);
        lcnt[tid] = 0;
    }

    const int id0 = pblk * 2048 + wave * 512 + lane;
    v2f px[PPAIR], py[PPAIR], pz[PPAIR], pw[PPAIR];
#pragma unroll
    for (int u = 0; u < PPAIR; ++u) {
        int ia = id0 + (2 * u) * 64, ib = id0 + (2 * u + 1) * 64;
        bool va = ia < NPTS, vb = ib < NPTS;
        int ca = va ? ia : 0, cb = vb ? ib : 0;
        float xa = xyz[3 * ca + 0], ya = xyz[3 * ca + 1], za = xyz[3 * ca + 2];
        float xb = xyz[3 * cb + 0], yb = xyz[3 * cb + 1], zb = xyz[3 * cb + 2];
        px[u] = (v2f){xa, xb}; py[u] = (v2f){ya, yb}; pz[u] = (v2f){za, zb};
        pw[u] = (v2f){va ? -0.5f * fmaf(xa, xa, fmaf(ya, ya, za * za)) : -INFINITY,
                      vb ? -0.5f * fmaf(xb, xb, fmaf(yb, yb, zb * zb)) : -INFINITY};
    }
    __syncthreads();

    auto emit = [&](int r, float sc, int id) {
        int slot = atomicAdd(&lcnt[r], 1);             // LDS atomic
        float2 e = make_float2(sc, __int_as_float(id));
        if (slot < LCAP) lbuf[r][slot] = e;
        else {                                         // rare overflow
            int gs = atomicAdd(&cnt[rbase + r], 1);
            if (gs < CAP) cand[((rbase + r) << 7) + gs] = e;
        }
    };

#pragma unroll 4
    for (int r = 0; r < RPBS; ++r) {
        float4 rp = rsh[r];                            // direct LDS read
        const v2f rx = (v2f){rp.x, rp.x}, ry = (v2f){rp.y, rp.y}, rz = (v2f){rp.z, rp.z};
        v2f s[PPAIR];
        v2f a0, a1;
        {
            v2f t = __builtin_elementwise_fma(pz[0], rz, pw[0]);
            t = __builtin_elementwise_fma(py[0], ry, t);
            t = __builtin_elementwise_fma(px[0], rx, t);
            s[0] = t; a0 = t;
            t = __builtin_elementwise_fma(pz[1], rz, pw[1]);
            t = __builtin_elementwise_fma(py[1], ry, t);
            t = __builtin_elementwise_fma(px[1], rx, t);
            s[1] = t; a1 = t;
            t = __builtin_elementwise_fma(pz[2], rz, pw[2]);
            t = __builtin_elementwise_fma(py[2], ry, t);
            t = __builtin_elementwise_fma(px[2], rx, t);
            s[2] = t; a0 = __builtin_elementwise_max(a0, t);
            t = __builtin_elementwise_fma(pz[3], rz, pw[3]);
            t = __builtin_elementwise_fma(py[3], ry, t);
            t = __builtin_elementwise_fma(px[3], rx, t);
            s[3] = t; a1 = __builtin_elementwise_max(a1, t);
        }
        v2f am = __builtin_elementwise_max(a0, a1);
        float hm = fmaxf(am.x, am.y);

        if (__ballot(hm >= rp.w)) {                    // rare wave-level gate
#pragma unroll
            for (int u = 0; u < PPAIR; ++u) {
                if (__ballot(s[u].x >= rp.w)) {        // per-element uniform gate
                    if (s[u].x >= rp.w) emit(r, s[u].x, id0 + (2 * u) * 64);
                }
                if (__ballot(s[u].y >= rp.w)) {
                    if (s[u].y >= rp.w) emit(r, s[u].y, id0 + (2 * u + 1) * 64);
                }
            }
        }
    }

    __syncthreads();
    if (tid < RPBS) {                                  // bulk flush: 1 atomic/ray
        int n = lcnt[tid];
        n = n < LCAP ? n : LCAP;
        if (n > 0) {
            const int rayid = rbase + tid;
            int base = atomicAdd(&cnt[rayid], n);
            for (int j = 0; j < n; ++j) {
                int slot = base + j;
                if (slot < CAP) cand[(rayid << 7) + slot] = lbuf[tid][j];
            }
        }
    }
}

// ---------------------------------------------------------------------------
// merge: wave per ray (proven R6 body). Coalesced candidate load, top-12 via
// 12 wave-argmax rounds on packed keys, parallel f64 re-rank, rgb.
// ---------------------------------------------------------------------------
__global__ __launch_bounds__(256) void merge_kernel(const float* __restrict__ ro,
                                                    const float* __restrict__ rd,
                                                    const int* __restrict__ cnt,
                                                    const float2* __restrict__ cand,
                                                    const float* __restrict__ xyz,
                                                    const float* __restrict__ fdc,
                                                    const float* __restrict__ opac,
                                                    float* __restrict__ out) {
    const int wave = threadIdx.x >> 6, lane = threadIdx.x & 63;
    const int ray = blockIdx.x * 4 + wave;

    int n = cnt[ray];
    n = n < CAP ? n : CAP;

    const float2* cl = cand + (ray << 7);
    float2 e0 = cl[lane];                              // coalesced 512B wave-load
    float2 e1 = cl[64 + lane];
    int id0 = __float_as_int(e0.y), id1 = __float_as_int(e1.y);

    unsigned long long k0 = mkkey(e0.x, id0, lane < n);
    unsigned long long k1 = mkkey(e1.x, id1, lane + 64 < n);

    int sel = -1;                                      // lane j holds j-th best id
    unsigned long long kl = k0 > k1 ? k0 : k1;
#pragma unroll
    for (int j = 0; j < KMER; ++j) {
        unsigned long long m = kl;
#pragma unroll
        for (int off = 1; off < 64; off <<= 1) {
            unsigned long long o = __shfl_xor(m, off);
            m = m > o ? m : o;
        }
        bool win = (kl == m) && (m != 0ull);
        int wid = (k0 >= k1) ? id0 : id1;
        unsigned long long wmask = __ballot(win);
        int wl = __ffsll(wmask) - 1;                   // unique winner (keys unique)
        int bid = __shfl(wid, wl & 63);
        if (m == 0ull) bid = -1;
        if (lane == j) sel = bid;
        if (win) {
            if (k0 >= k1) k0 = 0ull; else k1 = 0ull;
            kl = k0 > k1 ? k0 : k1;
        }
    }

    float ox = ro[3 * ray + 0], oy = ro[3 * ray + 1], oz = ro[3 * ray + 2];
    float dx = rd[3 * ray + 0], dy = rd[3 * ray + 1], dz = rd[3 * ray + 2];
    float cxf, cyf, czf;
    {
#pragma clang fp contract(off)
        cxf = ox + dx * 3.0f;
        cyf = oy + dy * 3.0f;
        czf = oz + dz * 3.0f;
    }
    double Cx = (double)cxf, Cy = (double)cyf, Cz = (double)czf;
    double cn = Cx * Cx + Cy * Cy + Cz * Cz;

    bool valid = (lane < KMER) && (sel >= 0);
    int pid = valid ? sel : 0;
    double X = (double)xyz[3 * pid + 0];
    double Y = (double)xyz[3 * pid + 1];
    double Z = (double)xyz[3 * pid + 2];
    double sq = valid ? (cn + (X * X + Y * Y + Z * Z) - 2.0 * (Cx * X + Cy * Y + Cz * Z))
                      : (double)INFINITY;
    int cid = valid ? sel : 0x7fffffff;

    int rank = 0;
#pragma unroll
    for (int k = 0; k < KMER; ++k) {                   // rank among the 12
        double sk = __shfl(sq, k);
        int    ik = __shfl(cid, k);
        if ((sk < sq) || (sk == sq && ik < cid)) ++rank;
    }

    bool take = valid && (rank < KTOP);
    float w = 0.0f, rr = 0.0f, gg = 0.0f, bb = 0.0f;
    if (take) {                                        // parallel gathers, 10 lanes
        float dd = sqrtf(fmaxf((float)sq, 0.0f));
        w  = expf(-0.1f * dd) * sigm(opac[pid]);
        rr = w * sigm(fdc[3 * pid + 0]);
        gg = w * sigm(fdc[3 * pid + 1]);
        bb = w * sigm(fdc[3 * pid + 2]);
    }
#pragma unroll
    for (int off = 1; off < 64; off <<= 1) {
        w  += __shfl_xor(w,  off);
        rr += __shfl_xor(rr, off);
        gg += __shfl_xor(gg, off);
        bb += __shfl_xor(bb, off);
    }
    if (lane == 0) {
        float inv = 1.0f / (w + 1e-8f);
        out[3 * ray + 0] = rr * inv;
        out[3 * ray + 1] = gg * inv;
        out[3 * ray + 2] = bb * inv;
    }
}

// ---------------------------------------------------------------------------
extern "C" void kernel_launch(void* const* d_in, const int* in_sizes, int n_in,
                              void* d_out, int out_size, void* d_ws, size_t ws_size,
                              hipStream_t stream) {
    const float* rays_o = (const float*)d_in[0];
    const float* rays_d = (const float*)d_in[1];
    const float* xyz    = (const float*)d_in[2];
    const float* fdc    = (const float*)d_in[3];
    const float* opac   = (const float*)d_in[4];
    float* out = (float*)d_out;

    // ws: theta 16KB | cnt 16KB | cand 4.0MB
    char* w = (char*)d_ws;
    float*  theta  = (float*)w;  w += (size_t)NRAYS * 4;
    int*    cnt    = (int*)w;    w += (size_t)NRAYS * 4;
    float2* cand   = (float2*)w;

    theta_kernel<<<NRAYS / TRAYS, 256, 0, stream>>>(xyz, rays_o, rays_d, theta, cnt);
    scan_kernel<<<dim3(SBLK, RCS), 256, 0, stream>>>(xyz, rays_o, rays_d, theta, cnt, cand);
    merge_kernel<<<NRAYS / 4, 256, 0, stream>>>(rays_o, rays_d, cnt, cand, xyz, fdc, opac, out);
}